// Round 5
// baseline (286.250 us; speedup 1.0000x reference)
//
#include <hip/hip_runtime.h>
#include <math.h>

// ---------------------------------------------------------------------------
// UltraMem forward, MI355X. B=2 N=1024 DIM=1024 DQK=128 NUM_KEYS=256 TOPK=32
// RANK=2 HEADS=2 DV=512 KCONV=5.
// ---------------------------------------------------------------------------

#define ROWS 2048            // B*N

// ======================= 2x2 SVD (LAPACK dgesdd replica) ====================
__device__ inline double dsgn(double x, double y) { return (y >= 0.0) ? fabs(x) : -fabs(x); }

__device__ void dlasv2_dev(double f, double g, double h,
                           double& ssmin, double& ssmax,
                           double& snr, double& csr, double& snl, double& csl)
{
  const double EPSD = 2.2204460492503131e-16;
  double ft = f, fa = fabs(f), ht = h, ha = fabs(h);
  int pmax = 1;
  bool swp = (ha > fa);
  if (swp) { pmax = 3; double tp = ft; ft = ht; ht = tp; tp = fa; fa = ha; ha = tp; }
  double gt = g, ga = fabs(gt);
  double clt = 0.0, crt = 0.0, slt = 0.0, srt = 0.0;
  if (ga == 0.0) {
    ssmin = ha; ssmax = fa; clt = 1.0; crt = 1.0; slt = 0.0; srt = 0.0;
  } else {
    bool gasmal = true;
    if (ga > fa) {
      pmax = 2;
      if ((fa / ga) < EPSD) {
        gasmal = false;
        ssmax = ga;
        if (ha > 1.0) ssmin = fa / (ga / ha); else ssmin = (fa / ga) * ha;
        clt = 1.0; slt = ht / gt; srt = 1.0; crt = ft / gt;
      }
    }
    if (gasmal) {
      double dd = fa - ha, l;
      if (dd == fa) l = 1.0; else l = dd / fa;
      double m  = gt / ft;
      double t  = 2.0 - l;
      double mm = m * m, tt = t * t;
      double s  = sqrt(tt + mm);
      double r  = (l == 0.0) ? fabs(m) : sqrt(l * l + mm);
      double a  = 0.5 * (s + r);
      ssmin = ha / a;
      ssmax = fa * a;
      if (mm == 0.0) {
        if (l == 0.0) t = dsgn(2.0, ft) * dsgn(1.0, gt);
        else          t = gt / dsgn(dd, ft) + m / t;
      } else {
        t = (m / (s + t) + m / (r + l)) * (1.0 + a);
      }
      double ll = sqrt(t * t + 4.0);
      crt = 2.0 / ll;
      srt = t / ll;
      clt = (crt + srt * m) / a;
      slt = (ht / ft) * srt / a;
    }
  }
  if (swp) { csl = srt; snl = crt; csr = slt; snr = clt; }
  else     { csl = clt; snl = slt; csr = crt; snr = srt; }
  double tsign = 1.0;
  if (pmax == 1) tsign = dsgn(1.0, csr) * dsgn(1.0, csl) * dsgn(1.0, f);
  if (pmax == 2) tsign = dsgn(1.0, snr) * dsgn(1.0, csl) * dsgn(1.0, g);
  if (pmax == 3) tsign = dsgn(1.0, snr) * dsgn(1.0, snl) * dsgn(1.0, h);
  ssmax = dsgn(ssmax, tsign);
  ssmin = dsgn(ssmin, tsign * dsgn(1.0, f) * dsgn(1.0, h));
}

__global__ void svd_kernel(const float* __restrict__ core, float* __restrict__ misc,
                           float* __restrict__ aux_out)
{
  if (threadIdx.x != 0 || blockIdx.x != 0) return;
  double aux = 0.0;
  for (int hh = 0; hh < 2; hh++) {
    double a = (double)core[hh * 4 + 0];
    double b = (double)core[hh * 4 + 1];
    double c = (double)core[hh * 4 + 2];
    double d = (double)core[hh * 4 + 3];
    double tau = 0.0, v2 = 0.0, d1, e, d2;
    if (c != 0.0) {
      double nrm  = sqrt(a * a + c * c);
      double beta = (a >= 0.0) ? -nrm : nrm;
      tau = (beta - a) / beta;
      v2  = c / (a - beta);
      double wsum = b + v2 * d;
      d1 = beta;
      e  = b - tau * wsum;
      d2 = d - tau * v2 * wsum;
    } else { d1 = a; e = b; d2 = d; }
    double ssmin, ssmax, snr, csr, snl, csl;
    dlasv2_dev(d1, e, d2, ssmin, ssmax, snr, csr, snl, csl);
    double t0 = csl + v2 * snl;
    double u0 = csl - tau * t0;
    double u1 = snl - tau * v2 * t0;
    double sg = (ssmax < 0.0) ? -1.0 : 1.0;
    misc[hh * 2 + 0]     = (float)u0;
    misc[hh * 2 + 1]     = (float)u1;
    misc[4 + hh * 2 + 0] = (float)(sg * csr);
    misc[4 + hh * 2 + 1] = (float)(sg * snr);
    double s2 = fabs(ssmin);
    double rl = s2 - 0.15; if (rl < 0.0) rl = 0.0;
    aux += rl * rl;
  }
  aux_out[0] = (float)(aux * 0.1);
}

// ====== fused RMSNorm + depthwise causal conv + bias (8 rows / block) =======
__global__ __launch_bounds__(256) void conv_kernel(const float* __restrict__ tokens,
                                                   const float* __restrict__ rms_w,
                                                   const float* __restrict__ conv_w,
                                                   const float* __restrict__ conv_b,
                                                   float* __restrict__ x2)
{
  __shared__ float x_l[12][1024];     // rows row0-4 .. row0+7
  __shared__ float red[12][4];
  __shared__ float inv_s[12];
  const int t    = threadIdx.x;
  const int row0 = blockIdx.x * 8;
  const int n0   = row0 & 1023;       // 8-aligned => whole block same batch
  const int c0   = t * 4;

  float sq[12];
  #pragma unroll
  for (int s = 0; s < 12; s++) {
    float4 v = make_float4(0.f, 0.f, 0.f, 0.f);
    if (n0 - 4 + s >= 0)
      v = *(const float4*)(tokens + (size_t)(row0 - 4 + s) * 1024 + c0);
    *(float4*)&x_l[s][c0] = v;
    sq[s] = v.x * v.x + v.y * v.y + v.z * v.z + v.w * v.w;
  }
  #pragma unroll
  for (int off = 32; off; off >>= 1) {
    #pragma unroll
    for (int s = 0; s < 12; s++) sq[s] += __shfl_down(sq[s], off, 64);
  }
  const int lane = t & 63, wv_id = t >> 6;
  if (lane == 0) {
    #pragma unroll
    for (int s = 0; s < 12; s++) red[s][wv_id] = sq[s];
  }
  __syncthreads();
  if (t < 12)
    inv_s[t] = rsqrtf((red[t][0] + red[t][1] + red[t][2] + red[t][3]) * (1.0f / 1024.0f)
                      + 1.1920929e-07f);
  __syncthreads();
  #pragma unroll
  for (int s = 0; s < 12; s++) {
    float iv = inv_s[s];
    float4 v = *(float4*)&x_l[s][c0];
    v.x *= iv; v.y *= iv; v.z *= iv; v.w *= iv;
    *(float4*)&x_l[s][c0] = v;
  }
  float wv[20];
  const float* cw = conv_w + (size_t)c0 * 5;
  #pragma unroll
  for (int i = 0; i < 5; i++) {
    float4 u = *(const float4*)(cw + i * 4);
    wv[i * 4 + 0] = u.x; wv[i * 4 + 1] = u.y; wv[i * 4 + 2] = u.z; wv[i * 4 + 3] = u.w;
  }
  float4 rw = *(const float4*)(rms_w + c0);
  float4 cb = *(const float4*)(conv_b + c0);
  #pragma unroll
  for (int r = 0; r < 8; r++) {
    float4 acc = make_float4(0.f, 0.f, 0.f, 0.f);
    #pragma unroll
    for (int k = 0; k < 5; k++) {
      float4 x4 = *(const float4*)&x_l[r + k][c0];
      acc.x = fmaf(x4.x, wv[0 * 5 + k], acc.x);
      acc.y = fmaf(x4.y, wv[1 * 5 + k], acc.y);
      acc.z = fmaf(x4.z, wv[2 * 5 + k], acc.z);
      acc.w = fmaf(x4.w, wv[3 * 5 + k], acc.w);
    }
    acc.x = acc.x * rw.x + cb.x;
    acc.y = acc.y * rw.y + cb.y;
    acc.z = acc.z * rw.z + cb.z;
    acc.w = acc.w * rw.w + cb.w;
    *(float4*)(x2 + (size_t)(row0 + r) * 1024 + c0) = acc;
  }
}

// ============== generic 64-row x 128-col fp32 GEMM tile =====================
__global__ __launch_bounds__(256) void gemm_kernel(const float* __restrict__ A, int lda,
                                                   const float* __restrict__ Bm, int ldb,
                                                   float* __restrict__ C, int ldc,
                                                   int koffy, int coffy, int poffy)
{
  __shared__ __align__(16) float a_lds[32 * 64];    // [k][row]
  __shared__ __align__(16) float b_lds[32 * 128];   // [k][col]
  const int t  = threadIdx.x;
  const int rb = blockIdx.x * 64;
  const int kb = blockIdx.y * koffy;
  const int cb = blockIdx.y * coffy;
  C += (size_t)blockIdx.y * (size_t)poffy;
  const int tx = t & 31, ty = t >> 5;
  const int c0 = tx * 4, r0 = ty * 8;
  float acc[8][4];
  #pragma unroll
  for (int i = 0; i < 8; i++)
    #pragma unroll
    for (int j = 0; j < 4; j++) acc[i][j] = 0.0f;

  const int ra = t & 63,  kqa = (t >> 6) * 8;
  const int ob = t >> 1,  kqb = (t & 1) * 16;

  for (int kt = 0; kt < 4; kt++) {
    const int k0 = kb + kt * 32;
    {
      const float* ap = A + (size_t)(rb + ra) * lda + k0 + kqa;
      float4 a0 = *(const float4*)(ap);
      float4 a1 = *(const float4*)(ap + 4);
      a_lds[(kqa + 0) * 64 + ra] = a0.x;
      a_lds[(kqa + 1) * 64 + ra] = a0.y;
      a_lds[(kqa + 2) * 64 + ra] = a0.z;
      a_lds[(kqa + 3) * 64 + ra] = a0.w;
      a_lds[(kqa + 4) * 64 + ra] = a1.x;
      a_lds[(kqa + 5) * 64 + ra] = a1.y;
      a_lds[(kqa + 6) * 64 + ra] = a1.z;
      a_lds[(kqa + 7) * 64 + ra] = a1.w;
    }
    {
      const float* bp = Bm + (size_t)(cb + ob) * ldb + k0 + kqb;
      float4 b0 = *(const float4*)(bp);
      float4 b1 = *(const float4*)(bp + 4);
      float4 b2 = *(const float4*)(bp + 8);
      float4 b3 = *(const float4*)(bp + 12);
      b_lds[(kqb +  0) * 128 + ob] = b0.x;
      b_lds[(kqb +  1) * 128 + ob] = b0.y;
      b_lds[(kqb +  2) * 128 + ob] = b0.z;
      b_lds[(kqb +  3) * 128 + ob] = b0.w;
      b_lds[(kqb +  4) * 128 + ob] = b1.x;
      b_lds[(kqb +  5) * 128 + ob] = b1.y;
      b_lds[(kqb +  6) * 128 + ob] = b1.z;
      b_lds[(kqb +  7) * 128 + ob] = b1.w;
      b_lds[(kqb +  8) * 128 + ob] = b2.x;
      b_lds[(kqb +  9) * 128 + ob] = b2.y;
      b_lds[(kqb + 10) * 128 + ob] = b2.z;
      b_lds[(kqb + 11) * 128 + ob] = b2.w;
      b_lds[(kqb + 12) * 128 + ob] = b3.x;
      b_lds[(kqb + 13) * 128 + ob] = b3.y;
      b_lds[(kqb + 14) * 128 + ob] = b3.z;
      b_lds[(kqb + 15) * 128 + ob] = b3.w;
    }
    __syncthreads();
    #pragma unroll
    for (int k = 0; k < 32; k++) {
      float4 av0 = *(const float4*)(a_lds + k * 64 + r0);
      float4 av1 = *(const float4*)(a_lds + k * 64 + r0 + 4);
      float4 bv  = *(const float4*)(b_lds + k * 128 + c0);
      float ar[8] = {av0.x, av0.y, av0.z, av0.w, av1.x, av1.y, av1.z, av1.w};
      float br[4] = {bv.x, bv.y, bv.z, bv.w};
      #pragma unroll
      for (int i = 0; i < 8; i++)
        #pragma unroll
        for (int j = 0; j < 4; j++)
          acc[i][j] = fmaf(ar[i], br[j], acc[i][j]);
    }
    __syncthreads();
  }
  #pragma unroll
  for (int i = 0; i < 8; i++) {
    float4 o4; o4.x = acc[i][0]; o4.y = acc[i][1]; o4.z = acc[i][2]; o4.w = acc[i][3];
    *(float4*)(C + (size_t)(rb + r0 + i) * ldc + cb + c0) = o4;
  }
}

// ================= K-partial reduce + LayerNorm on q ========================
__global__ __launch_bounds__(128) void ln_kernel(const float* __restrict__ qpart,
                                                 const float* __restrict__ qln_w,
                                                 float* __restrict__ q)
{
  const int row = blockIdx.x, o = threadIdx.x;
  float v = 0.0f;
  #pragma unroll
  for (int g = 0; g < 8; g++) v += qpart[(size_t)g * (ROWS * 128) + (size_t)row * 128 + o];
  __shared__ float red[2];
  float s = v;
  for (int off = 32; off; off >>= 1) s += __shfl_down(s, off, 64);
  if ((o & 63) == 0) red[o >> 6] = s;
  __syncthreads();
  float mu  = (red[0] + red[1]) * (1.0f / 128.0f);
  float dv  = v - mu;
  float s2  = dv * dv;
  for (int off = 32; off; off >>= 1) s2 += __shfl_down(s2, off, 64);
  __syncthreads();
  if ((o & 63) == 0) red[o >> 6] = s2;
  __syncthreads();
  float var = (red[0] + red[1]) * (1.0f / 128.0f);
  q[(size_t)row * 128 + o] = dv * rsqrtf(var + 1e-5f) * qln_w[o];
}

// ======================== ballot radix-select helpers =======================
__device__ inline unsigned f2ord(float f) {
  unsigned u = __float_as_uint(f);
  return (u & 0x80000000u) ? ~u : (u | 0x80000000u);
}
__device__ inline int lpc(unsigned long long m) {
  return __builtin_amdgcn_mbcnt_hi((unsigned)(m >> 32),
         __builtin_amdgcn_mbcnt_lo((unsigned)m, 0));
}

// ========= selection: phase1 top-32, phase2 top-32, merge -> global =========
__global__ __launch_bounds__(256) void select_kernel(const float* __restrict__ sc,
                                                     const float* __restrict__ misc,
                                                     const float* __restrict__ core,
                                                     int*   __restrict__ sel_i,
                                                     float* __restrict__ sel_w)
{
  // sc row layout is already 4 contiguous planes of 256: row_r0,row_r1,col_r0,col_r1
  __shared__ __align__(16) float s_pl[1024];
  __shared__ int   tkbuf[4][32];     // (h,side) -> unsorted top-32 m-indices
  __shared__ float mvals[4][32];     // (h,half) -> unsorted top-32 score values
  __shared__ int   mcand[4][32];     // candidate ids (slot-based, 0..1023)

  const int row = blockIdx.x;
  const int tid = threadIdx.x;
  ((float4*)s_pl)[tid] = ((const float4*)(sc + (size_t)row * 1024))[tid];
  __syncthreads();

  const int w = tid >> 6, lane = tid & 63;

  // ---- phase 1: wave w -> (head = w>>1, side = w&1), top-32 of 256 ----
  {
    const int h = w >> 1, side = w & 1;
    const float v0 = misc[side * 4 + h * 2 + 0];
    const float v1 = misc[side * 4 + h * 2 + 1];
    const float* p0 = s_pl + side * 512;       // rank-0 plane
    const float* p1 = p0 + 256;                // rank-1 plane
    const int mb = lane * 4;
    float4 a4 = *(const float4*)(p0 + mb);     // ds_read_b128, conflict-free
    float4 b4 = *(const float4*)(p1 + mb);
    unsigned kk[4];
    kk[0] = f2ord(a4.x * v0 + b4.x * v1);
    kk[1] = f2ord(a4.y * v0 + b4.y * v1);
    kk[2] = f2ord(a4.z * v0 + b4.z * v1);
    kk[3] = f2ord(a4.w * v0 + b4.w * v1);
    unsigned tau = 0u;
    #pragma unroll
    for (int b = 31; b >= 0; --b) {
      unsigned cand = tau | (1u << b);
      int cnt = 0;
      #pragma unroll
      for (int i = 0; i < 4; i++) cnt += __popcll(__ballot(kk[i] >= cand));
      if (cnt >= 32) tau = cand;
    }
    unsigned long long bG[4], bE[4];
    int cntG = 0, sbG = 0, sbE = 0;
    #pragma unroll
    for (int i = 0; i < 4; i++) {
      bG[i] = __ballot(kk[i] > tau);
      bE[i] = __ballot(kk[i] == tau);
      cntG += __popcll(bG[i]);
      sbG  += lpc(bG[i]);
      sbE  += lpc(bE[i]);
    }
    const int need = 32 - cntG;
    int runG = 0, runE = 0;
    #pragma unroll
    for (int i = 0; i < 4; i++) {
      if (kk[i] > tau)       { tkbuf[w][sbG + runG] = mb + i; runG++; }
      else if (kk[i] == tau) {
        int r = sbE + runE;
        if (r < need) tkbuf[w][cntG + r] = mb + i;
        runE++;
      }
    }
  }
  __syncthreads();

  // ---- phase 2: wave w -> (head = w>>1, half = w&1), top-32 of 512 ----
  {
    const int h = w >> 1, half = w & 1;
    const float c00 = core[h * 4 + 0], c01 = core[h * 4 + 1];
    const float c10 = core[h * 4 + 2], c11 = core[h * 4 + 3];
    const int i_glob = half * 16 + (lane >> 2);
    const int ri = tkbuf[h * 2 + 0][i_glob];
    const float fr0 = s_pl[ri], fr1 = s_pl[256 + ri];
    const float a0 = fr0 * c00 + fr1 * c10;
    const float a1 = fr0 * c01 + fr1 * c11;
    const int j0 = (lane & 3) * 8;
    float sv[8];
    unsigned kk[8];
    #pragma unroll
    for (int t2 = 0; t2 < 8; t2++) {
      int cj = tkbuf[h * 2 + 1][j0 + t2];
      sv[t2] = a0 * s_pl[512 + cj] + a1 * s_pl[768 + cj];
      kk[t2] = f2ord(sv[t2]);
    }
    unsigned tau = 0u;
    #pragma unroll
    for (int b = 31; b >= 0; --b) {
      unsigned cand = tau | (1u << b);
      int cnt = 0;
      #pragma unroll
      for (int i = 0; i < 8; i++) cnt += __popcll(__ballot(kk[i] >= cand));
      if (cnt >= 32) tau = cand;
    }
    unsigned long long bG[8], bE[8];
    int cntG = 0, sbG = 0, sbE = 0;
    #pragma unroll
    for (int i = 0; i < 8; i++) {
      bG[i] = __ballot(kk[i] > tau);
      bE[i] = __ballot(kk[i] == tau);
      cntG += __popcll(bG[i]);
      sbG  += lpc(bG[i]);
      sbE  += lpc(bE[i]);
    }
    const int need = 32 - cntG;
    int runG = 0, runE = 0;
    #pragma unroll
    for (int i = 0; i < 8; i++) {
      int c = i_glob * 32 + j0 + i;
      if (kk[i] > tau) {
        mvals[w][sbG + runG] = sv[i]; mcand[w][sbG + runG] = c; runG++;
      } else if (kk[i] == tau) {
        int r = sbE + runE;
        if (r < need) { mvals[w][cntG + r] = sv[i]; mcand[w][cntG + r] = c; }
        runE++;
      }
    }
  }
  __syncthreads();

  // ---- merge two half-lists per head by rank-count; emit to global ----
  if (w < 2) {
    const int h = w;
    const int half2 = lane >> 5, k = lane & 31;
    const float v = mvals[h * 2 + half2][k];
    const int   c = mcand[h * 2 + half2][k];
    int cnt = 0;
    #pragma unroll 8
    for (int j = 0; j < 64; j++) {
      float u = mvals[h * 2 + (j >> 5)][j & 31];
      int  uc = mcand[h * 2 + (j >> 5)][j & 31];
      cnt += (u > v || (u == v && uc < c)) ? 1 : 0;
    }
    if (cnt < 32) {
      int ii = c >> 5, jj = c & 31;
      sel_i[(size_t)row * 64 + h * 32 + cnt] = tkbuf[h * 2][ii] * 256 + tkbuf[h * 2 + 1][jj];
      sel_w[(size_t)row * 64 + h * 32 + cnt] = 1.0f / (1.0f + expf(-v));
    }
  }
}

// ======================= weighted gather-sum ================================
__global__ __launch_bounds__(256) void gather_kernel(const int*   __restrict__ sel_i,
                                                     const float* __restrict__ sel_w,
                                                     const float* __restrict__ memories,
                                                     float* __restrict__ out)
{
  __shared__ int   s_idx[64];
  __shared__ float s_w[64];
  const int row = blockIdx.x;
  const int tid = threadIdx.x;
  if (tid < 64) {
    s_idx[tid] = sel_i[(size_t)row * 64 + tid];
    s_w[tid]   = sel_w[(size_t)row * 64 + tid];
  }
  __syncthreads();
  const int h2 = tid >> 7;
  const int d4 = tid & 127;
  const float* mb = memories + d4 * 4;
  float ax = 0.f, ay = 0.f, az = 0.f, aw = 0.f;
  #pragma unroll
  for (int b = 0; b < 4; b++) {
    int   mi[8]; float wg[8]; float4 v[8];
    #pragma unroll
    for (int i = 0; i < 8; i++) {
      mi[i] = s_idx[h2 * 32 + b * 8 + i];
      wg[i] = s_w[h2 * 32 + b * 8 + i];
    }
    #pragma unroll
    for (int i = 0; i < 8; i++)
      v[i] = *(const float4*)(mb + (size_t)mi[i] * 512);
    #pragma unroll
    for (int i = 0; i < 8; i++) {
      ax = fmaf(wg[i], v[i].x, ax);
      ay = fmaf(wg[i], v[i].y, ay);
      az = fmaf(wg[i], v[i].z, az);
      aw = fmaf(wg[i], v[i].w, aw);
    }
  }
  float4 o4; o4.x = ax; o4.y = ay; o4.z = az; o4.w = aw;
  ((float4*)out)[(size_t)row * 256 + tid] = o4;
}

// ============================== launcher ====================================
extern "C" void kernel_launch(void* const* d_in, const int* in_sizes, int n_in,
                              void* d_out, int out_size, void* d_ws, size_t ws_size,
                              hipStream_t stream) {
  const float* tokens = (const float*)d_in[0];
  const float* rms_w  = (const float*)d_in[1];
  const float* conv_w = (const float*)d_in[2];
  const float* conv_b = (const float*)d_in[3];
  const float* wq     = (const float*)d_in[4];
  const float* qln_w  = (const float*)d_in[5];
  const float* keys   = (const float*)d_in[6];
  const float* core   = (const float*)d_in[7];
  const float* mems   = (const float*)d_in[8];
  float* out = (float*)d_out;
  float* ws  = (float*)d_ws;

  // workspace layout (floats); sc aliases x2 (dead after gemm1);
  // sel buffers alias qpart (dead after ln).
  float* misc   = ws;                          // 8
  float* x2     = ws + 4096;                   // 2048*1024
  float* qpart  = x2 + 2097152;                // 8 * 2048*128
  float* q      = qpart + 2097152;             // 2048*128
  float* sc     = x2;
  int*   sel_i  = (int*)qpart;                 // 2048*64
  float* sel_w  = qpart + 131072;              // 2048*64

  svd_kernel   <<<1, 64, 0, stream>>>(core, misc, out + 2097152);
  conv_kernel  <<<ROWS / 8, 256, 0, stream>>>(tokens, rms_w, conv_w, conv_b, x2);
  gemm_kernel  <<<dim3(32, 8), 256, 0, stream>>>(x2, 1024, wq, 1024,
                                                 qpart, 128, 128, 0, ROWS * 128);
  ln_kernel    <<<ROWS, 128, 0, stream>>>(qpart, qln_w, q);
  gemm_kernel  <<<dim3(32, 8), 256, 0, stream>>>(q, 128, keys, 128,
                                                 sc, 1024, 0, 128, 0);
  select_kernel<<<ROWS, 256, 0, stream>>>(sc, misc, core, sel_i, sel_w);
  gather_kernel<<<ROWS, 256, 0, stream>>>(sel_i, sel_w, mems, out);
}

// Round 6
// 277.559 us; speedup vs baseline: 1.0313x; 1.0313x over previous
//
#include <hip/hip_runtime.h>
#include <math.h>

// ---------------------------------------------------------------------------
// UltraMem forward, MI355X. B=2 N=1024 DIM=1024 DQK=128 NUM_KEYS=256 TOPK=32
// RANK=2 HEADS=2 DV=512 KCONV=5.
// ---------------------------------------------------------------------------

#define ROWS 2048            // B*N

// ======================= 2x2 SVD (LAPACK dgesdd replica) ====================
__device__ inline double dsgn(double x, double y) { return (y >= 0.0) ? fabs(x) : -fabs(x); }

__device__ void dlasv2_dev(double f, double g, double h,
                           double& ssmin, double& ssmax,
                           double& snr, double& csr, double& snl, double& csl)
{
  const double EPSD = 2.2204460492503131e-16;
  double ft = f, fa = fabs(f), ht = h, ha = fabs(h);
  int pmax = 1;
  bool swp = (ha > fa);
  if (swp) { pmax = 3; double tp = ft; ft = ht; ht = tp; tp = fa; fa = ha; ha = tp; }
  double gt = g, ga = fabs(gt);
  double clt = 0.0, crt = 0.0, slt = 0.0, srt = 0.0;
  if (ga == 0.0) {
    ssmin = ha; ssmax = fa; clt = 1.0; crt = 1.0; slt = 0.0; srt = 0.0;
  } else {
    bool gasmal = true;
    if (ga > fa) {
      pmax = 2;
      if ((fa / ga) < EPSD) {
        gasmal = false;
        ssmax = ga;
        if (ha > 1.0) ssmin = fa / (ga / ha); else ssmin = (fa / ga) * ha;
        clt = 1.0; slt = ht / gt; srt = 1.0; crt = ft / gt;
      }
    }
    if (gasmal) {
      double dd = fa - ha, l;
      if (dd == fa) l = 1.0; else l = dd / fa;
      double m  = gt / ft;
      double t  = 2.0 - l;
      double mm = m * m, tt = t * t;
      double s  = sqrt(tt + mm);
      double r  = (l == 0.0) ? fabs(m) : sqrt(l * l + mm);
      double a  = 0.5 * (s + r);
      ssmin = ha / a;
      ssmax = fa * a;
      if (mm == 0.0) {
        if (l == 0.0) t = dsgn(2.0, ft) * dsgn(1.0, gt);
        else          t = gt / dsgn(dd, ft) + m / t;
      } else {
        t = (m / (s + t) + m / (r + l)) * (1.0 + a);
      }
      double ll = sqrt(t * t + 4.0);
      crt = 2.0 / ll;
      srt = t / ll;
      clt = (crt + srt * m) / a;
      slt = (ht / ft) * srt / a;
    }
  }
  if (swp) { csl = srt; snl = crt; csr = slt; snr = clt; }
  else     { csl = clt; snl = slt; csr = crt; snr = srt; }
  double tsign = 1.0;
  if (pmax == 1) tsign = dsgn(1.0, csr) * dsgn(1.0, csl) * dsgn(1.0, f);
  if (pmax == 2) tsign = dsgn(1.0, snr) * dsgn(1.0, csl) * dsgn(1.0, g);
  if (pmax == 3) tsign = dsgn(1.0, snr) * dsgn(1.0, snl) * dsgn(1.0, h);
  ssmax = dsgn(ssmax, tsign);
  ssmin = dsgn(ssmin, tsign * dsgn(1.0, f) * dsgn(1.0, h));
}

__device__ void do_svd(const float* __restrict__ core, float* __restrict__ misc,
                       float* __restrict__ aux_out)
{
  double aux = 0.0;
  for (int hh = 0; hh < 2; hh++) {
    double a = (double)core[hh * 4 + 0];
    double b = (double)core[hh * 4 + 1];
    double c = (double)core[hh * 4 + 2];
    double d = (double)core[hh * 4 + 3];
    double tau = 0.0, v2 = 0.0, d1, e, d2;
    if (c != 0.0) {
      double nrm  = sqrt(a * a + c * c);
      double beta = (a >= 0.0) ? -nrm : nrm;
      tau = (beta - a) / beta;
      v2  = c / (a - beta);
      double wsum = b + v2 * d;
      d1 = beta;
      e  = b - tau * wsum;
      d2 = d - tau * v2 * wsum;
    } else { d1 = a; e = b; d2 = d; }
    double ssmin, ssmax, snr, csr, snl, csl;
    dlasv2_dev(d1, e, d2, ssmin, ssmax, snr, csr, snl, csl);
    double t0 = csl + v2 * snl;
    double u0 = csl - tau * t0;
    double u1 = snl - tau * v2 * t0;
    double sg = (ssmax < 0.0) ? -1.0 : 1.0;
    misc[hh * 2 + 0]     = (float)u0;
    misc[hh * 2 + 1]     = (float)u1;
    misc[4 + hh * 2 + 0] = (float)(sg * csr);
    misc[4 + hh * 2 + 1] = (float)(sg * snr);
    double s2 = fabs(ssmin);
    double rl = s2 - 0.15; if (rl < 0.0) rl = 0.0;
    aux += rl * rl;
  }
  aux_out[0] = (float)(aux * 0.1);
}

// == fused RMSNorm + depthwise causal conv + bias (8 rows / block) + svd =====
__global__ __launch_bounds__(256) void conv_kernel(const float* __restrict__ tokens,
                                                   const float* __restrict__ rms_w,
                                                   const float* __restrict__ conv_w,
                                                   const float* __restrict__ conv_b,
                                                   const float* __restrict__ core,
                                                   float* __restrict__ misc,
                                                   float* __restrict__ aux_out,
                                                   float* __restrict__ x2)
{
  __shared__ float x_l[12][1024];     // rows row0-4 .. row0+7
  __shared__ float red[12][4];
  __shared__ float inv_s[12];
  const int t    = threadIdx.x;
  const int row0 = blockIdx.x * 8;
  const int n0   = row0 & 1023;       // 8-aligned => whole block same batch
  const int c0   = t * 4;

  float sq[12];
  #pragma unroll
  for (int s = 0; s < 12; s++) {
    float4 v = make_float4(0.f, 0.f, 0.f, 0.f);
    if (n0 - 4 + s >= 0)
      v = *(const float4*)(tokens + (size_t)(row0 - 4 + s) * 1024 + c0);
    *(float4*)&x_l[s][c0] = v;
    sq[s] = v.x * v.x + v.y * v.y + v.z * v.z + v.w * v.w;
  }
  #pragma unroll
  for (int off = 32; off; off >>= 1) {
    #pragma unroll
    for (int s = 0; s < 12; s++) sq[s] += __shfl_down(sq[s], off, 64);
  }
  const int lane = t & 63, wv_id = t >> 6;
  if (lane == 0) {
    #pragma unroll
    for (int s = 0; s < 12; s++) red[s][wv_id] = sq[s];
  }
  __syncthreads();
  if (t < 12)
    inv_s[t] = rsqrtf((red[t][0] + red[t][1] + red[t][2] + red[t][3]) * (1.0f / 1024.0f)
                      + 1.1920929e-07f);
  __syncthreads();
  #pragma unroll
  for (int s = 0; s < 12; s++) {
    float iv = inv_s[s];
    float4 v = *(float4*)&x_l[s][c0];
    v.x *= iv; v.y *= iv; v.z *= iv; v.w *= iv;
    *(float4*)&x_l[s][c0] = v;
  }
  float wv[20];
  const float* cw = conv_w + (size_t)c0 * 5;
  #pragma unroll
  for (int i = 0; i < 5; i++) {
    float4 u = *(const float4*)(cw + i * 4);
    wv[i * 4 + 0] = u.x; wv[i * 4 + 1] = u.y; wv[i * 4 + 2] = u.z; wv[i * 4 + 3] = u.w;
  }
  float4 rw = *(const float4*)(rms_w + c0);
  float4 cb = *(const float4*)(conv_b + c0);
  #pragma unroll
  for (int r = 0; r < 8; r++) {
    float4 acc = make_float4(0.f, 0.f, 0.f, 0.f);
    #pragma unroll
    for (int k = 0; k < 5; k++) {
      float4 x4 = *(const float4*)&x_l[r + k][c0];
      acc.x = fmaf(x4.x, wv[0 * 5 + k], acc.x);
      acc.y = fmaf(x4.y, wv[1 * 5 + k], acc.y);
      acc.z = fmaf(x4.z, wv[2 * 5 + k], acc.z);
      acc.w = fmaf(x4.w, wv[3 * 5 + k], acc.w);
    }
    acc.x = acc.x * rw.x + cb.x;
    acc.y = acc.y * rw.y + cb.y;
    acc.z = acc.z * rw.z + cb.z;
    acc.w = acc.w * rw.w + cb.w;
    *(float4*)(x2 + (size_t)(row0 + r) * 1024 + c0) = acc;
  }
  if (blockIdx.x == 0 && t == 0) do_svd(core, misc, aux_out);
}

// ============== generic 64-row x 128-col fp32 GEMM tile (gemm1) =============
__global__ __launch_bounds__(256) void gemm_kernel(const float* __restrict__ A, int lda,
                                                   const float* __restrict__ Bm, int ldb,
                                                   float* __restrict__ C, int ldc,
                                                   int koffy, int coffy, int poffy)
{
  __shared__ __align__(16) float a_lds[32 * 64];    // [k][row]
  __shared__ __align__(16) float b_lds[32 * 128];   // [k][col]
  const int t  = threadIdx.x;
  const int rb = blockIdx.x * 64;
  const int kb = blockIdx.y * koffy;
  const int cb = blockIdx.y * coffy;
  C += (size_t)blockIdx.y * (size_t)poffy;
  const int tx = t & 31, ty = t >> 5;
  const int c0 = tx * 4, r0 = ty * 8;
  float acc[8][4];
  #pragma unroll
  for (int i = 0; i < 8; i++)
    #pragma unroll
    for (int j = 0; j < 4; j++) acc[i][j] = 0.0f;

  const int ra = t & 63,  kqa = (t >> 6) * 8;
  const int ob = t >> 1,  kqb = (t & 1) * 16;

  for (int kt = 0; kt < 4; kt++) {
    const int k0 = kb + kt * 32;
    {
      const float* ap = A + (size_t)(rb + ra) * lda + k0 + kqa;
      float4 a0 = *(const float4*)(ap);
      float4 a1 = *(const float4*)(ap + 4);
      a_lds[(kqa + 0) * 64 + ra] = a0.x;
      a_lds[(kqa + 1) * 64 + ra] = a0.y;
      a_lds[(kqa + 2) * 64 + ra] = a0.z;
      a_lds[(kqa + 3) * 64 + ra] = a0.w;
      a_lds[(kqa + 4) * 64 + ra] = a1.x;
      a_lds[(kqa + 5) * 64 + ra] = a1.y;
      a_lds[(kqa + 6) * 64 + ra] = a1.z;
      a_lds[(kqa + 7) * 64 + ra] = a1.w;
    }
    {
      const float* bp = Bm + (size_t)(cb + ob) * ldb + k0 + kqb;
      float4 b0 = *(const float4*)(bp);
      float4 b1 = *(const float4*)(bp + 4);
      float4 b2 = *(const float4*)(bp + 8);
      float4 b3 = *(const float4*)(bp + 12);
      b_lds[(kqb +  0) * 128 + ob] = b0.x;
      b_lds[(kqb +  1) * 128 + ob] = b0.y;
      b_lds[(kqb +  2) * 128 + ob] = b0.z;
      b_lds[(kqb +  3) * 128 + ob] = b0.w;
      b_lds[(kqb +  4) * 128 + ob] = b1.x;
      b_lds[(kqb +  5) * 128 + ob] = b1.y;
      b_lds[(kqb +  6) * 128 + ob] = b1.z;
      b_lds[(kqb +  7) * 128 + ob] = b1.w;
      b_lds[(kqb +  8) * 128 + ob] = b2.x;
      b_lds[(kqb +  9) * 128 + ob] = b2.y;
      b_lds[(kqb + 10) * 128 + ob] = b2.z;
      b_lds[(kqb + 11) * 128 + ob] = b2.w;
      b_lds[(kqb + 12) * 128 + ob] = b3.x;
      b_lds[(kqb + 13) * 128 + ob] = b3.y;
      b_lds[(kqb + 14) * 128 + ob] = b3.z;
      b_lds[(kqb + 15) * 128 + ob] = b3.w;
    }
    __syncthreads();
    #pragma unroll
    for (int k = 0; k < 32; k++) {
      float4 av0 = *(const float4*)(a_lds + k * 64 + r0);
      float4 av1 = *(const float4*)(a_lds + k * 64 + r0 + 4);
      float4 bv  = *(const float4*)(b_lds + k * 128 + c0);
      float ar[8] = {av0.x, av0.y, av0.z, av0.w, av1.x, av1.y, av1.z, av1.w};
      float br[4] = {bv.x, bv.y, bv.z, bv.w};
      #pragma unroll
      for (int i = 0; i < 8; i++)
        #pragma unroll
        for (int j = 0; j < 4; j++)
          acc[i][j] = fmaf(ar[i], br[j], acc[i][j]);
    }
    __syncthreads();
  }
  #pragma unroll
  for (int i = 0; i < 8; i++) {
    float4 o4; o4.x = acc[i][0]; o4.y = acc[i][1]; o4.z = acc[i][2]; o4.w = acc[i][3];
    *(float4*)(C + (size_t)(rb + r0 + i) * ldc + cb + c0) = o4;
  }
}

// ========== gemm2 with fused plane-reduce + LayerNorm on the A side =========
// A[row][k] = LN(sum_g qpart[g][row][k]) * qln_w[k];  C = A * keys^T
__global__ __launch_bounds__(256) void gemm2ln_kernel(const float* __restrict__ qpart,
                                                      const float* __restrict__ qln_w,
                                                      const float* __restrict__ keys,
                                                      float* __restrict__ C)
{
  __shared__ __align__(16) float a_l[128 * 64];     // [k][row], normalized
  __shared__ __align__(16) float b_lds[32 * 128];   // [k][col]
  const int t  = threadIdx.x;
  const int rb = blockIdx.x * 64;
  const int cb = blockIdx.y * 128;

  // ---- coalesced plane-reduce: lane32 covers k-quad, g32+8j covers rows ----
  const int l32 = t & 31;          // k cols l32*4 .. +3
  const int g32 = t >> 5;          // rows g32 + 8*j
  float vs[8][4];
  #pragma unroll
  for (int j = 0; j < 8; j++) { vs[j][0]=0.f; vs[j][1]=0.f; vs[j][2]=0.f; vs[j][3]=0.f; }
  #pragma unroll
  for (int g = 0; g < 8; g++) {
    const float* pg = qpart + (size_t)g * (ROWS * 128) + (size_t)rb * 128 + l32 * 4;
    #pragma unroll
    for (int j = 0; j < 8; j++) {
      float4 v = *(const float4*)(pg + (g32 + 8 * j) * 128);
      vs[j][0] += v.x; vs[j][1] += v.y; vs[j][2] += v.z; vs[j][3] += v.w;
    }
  }
  float4 qw = *(const float4*)(qln_w + l32 * 4);
  #pragma unroll
  for (int j = 0; j < 8; j++) {
    float s1 = vs[j][0] + vs[j][1] + vs[j][2] + vs[j][3];
    #pragma unroll
    for (int off = 16; off; off >>= 1) s1 += __shfl_xor(s1, off, 32);
    float mu = s1 * (1.0f / 128.0f);
    float d0 = vs[j][0] - mu, d1 = vs[j][1] - mu, d2 = vs[j][2] - mu, d3 = vs[j][3] - mu;
    float s2 = d0 * d0 + d1 * d1 + d2 * d2 + d3 * d3;
    #pragma unroll
    for (int off = 16; off; off >>= 1) s2 += __shfl_xor(s2, off, 32);
    float rstd = rsqrtf(s2 * (1.0f / 128.0f) + 1e-5f);
    const int row = g32 + 8 * j;
    // one-time transposed store; 32-way bank conflict is epilogue-only, ~0.6us
    a_l[(l32 * 4 + 0) * 64 + row] = d0 * rstd * qw.x;
    a_l[(l32 * 4 + 1) * 64 + row] = d1 * rstd * qw.y;
    a_l[(l32 * 4 + 2) * 64 + row] = d2 * rstd * qw.z;
    a_l[(l32 * 4 + 3) * 64 + row] = d3 * rstd * qw.w;
  }
  __syncthreads();

  const int tx = t & 31, ty = t >> 5;
  const int c0 = tx * 4, r0 = ty * 8;
  float acc[8][4];
  #pragma unroll
  for (int i = 0; i < 8; i++)
    #pragma unroll
    for (int j = 0; j < 4; j++) acc[i][j] = 0.0f;

  const int ob = t >> 1, kqb = (t & 1) * 16;
  for (int kt = 0; kt < 4; kt++) {
    const int k0 = kt * 32;
    {
      const float* bp = keys + (size_t)(cb + ob) * 128 + k0 + kqb;
      float4 b0 = *(const float4*)(bp);
      float4 b1 = *(const float4*)(bp + 4);
      float4 b2 = *(const float4*)(bp + 8);
      float4 b3 = *(const float4*)(bp + 12);
      b_lds[(kqb +  0) * 128 + ob] = b0.x;
      b_lds[(kqb +  1) * 128 + ob] = b0.y;
      b_lds[(kqb +  2) * 128 + ob] = b0.z;
      b_lds[(kqb +  3) * 128 + ob] = b0.w;
      b_lds[(kqb +  4) * 128 + ob] = b1.x;
      b_lds[(kqb +  5) * 128 + ob] = b1.y;
      b_lds[(kqb +  6) * 128 + ob] = b1.z;
      b_lds[(kqb +  7) * 128 + ob] = b1.w;
      b_lds[(kqb +  8) * 128 + ob] = b2.x;
      b_lds[(kqb +  9) * 128 + ob] = b2.y;
      b_lds[(kqb + 10) * 128 + ob] = b2.z;
      b_lds[(kqb + 11) * 128 + ob] = b2.w;
      b_lds[(kqb + 12) * 128 + ob] = b3.x;
      b_lds[(kqb + 13) * 128 + ob] = b3.y;
      b_lds[(kqb + 14) * 128 + ob] = b3.z;
      b_lds[(kqb + 15) * 128 + ob] = b3.w;
    }
    __syncthreads();
    #pragma unroll
    for (int k = 0; k < 32; k++) {
      float4 av0 = *(const float4*)(a_l + (k0 + k) * 64 + r0);
      float4 av1 = *(const float4*)(a_l + (k0 + k) * 64 + r0 + 4);
      float4 bv  = *(const float4*)(b_lds + k * 128 + c0);
      float ar[8] = {av0.x, av0.y, av0.z, av0.w, av1.x, av1.y, av1.z, av1.w};
      float br[4] = {bv.x, bv.y, bv.z, bv.w};
      #pragma unroll
      for (int i = 0; i < 8; i++)
        #pragma unroll
        for (int j = 0; j < 4; j++)
          acc[i][j] = fmaf(ar[i], br[j], acc[i][j]);
    }
    __syncthreads();
  }
  #pragma unroll
  for (int i = 0; i < 8; i++) {
    float4 o4; o4.x = acc[i][0]; o4.y = acc[i][1]; o4.z = acc[i][2]; o4.w = acc[i][3];
    *(float4*)(C + (size_t)(rb + r0 + i) * 1024 + cb + c0) = o4;
  }
}

// ======================== ballot radix-select helpers =======================
__device__ inline unsigned f2ord(float f) {
  unsigned u = __float_as_uint(f);
  return (u & 0x80000000u) ? ~u : (u | 0x80000000u);
}
__device__ inline int lpc(unsigned long long m) {
  return __builtin_amdgcn_mbcnt_hi((unsigned)(m >> 32),
         __builtin_amdgcn_mbcnt_lo((unsigned)m, 0));
}

// ======= fused tail: phase1 top-32, phase2 top-32, merge, gather-sum ========
__global__ __launch_bounds__(256) void tail_kernel(const float* __restrict__ sc,
                                                   const float* __restrict__ misc,
                                                   const float* __restrict__ core,
                                                   const float* __restrict__ memories,
                                                   float* __restrict__ out)
{
  // sc row = 4 contiguous planes of 256: row_r0,row_r1,col_r0,col_r1
  __shared__ __align__(16) float s_pl[1024];
  __shared__ int   tkbuf[4][32];
  __shared__ float mvals[4][32];
  __shared__ int   mcand[4][32];
  __shared__ int   s_idx[64];
  __shared__ float s_w[64];

  const int row = blockIdx.x;
  const int tid = threadIdx.x;
  ((float4*)s_pl)[tid] = ((const float4*)(sc + (size_t)row * 1024))[tid];
  __syncthreads();

  const int w = tid >> 6, lane = tid & 63;

  // ---- phase 1: wave w -> (head = w>>1, side = w&1), top-32 of 256 ----
  {
    const int h = w >> 1, side = w & 1;
    const float v0 = misc[side * 4 + h * 2 + 0];
    const float v1 = misc[side * 4 + h * 2 + 1];
    const float* p0 = s_pl + side * 512;
    const float* p1 = p0 + 256;
    const int mb = lane * 4;
    float4 a4 = *(const float4*)(p0 + mb);
    float4 b4 = *(const float4*)(p1 + mb);
    unsigned kk[4];
    kk[0] = f2ord(a4.x * v0 + b4.x * v1);
    kk[1] = f2ord(a4.y * v0 + b4.y * v1);
    kk[2] = f2ord(a4.z * v0 + b4.z * v1);
    kk[3] = f2ord(a4.w * v0 + b4.w * v1);
    unsigned tau = 0u;
    #pragma unroll
    for (int b = 31; b >= 0; --b) {
      unsigned cand = tau | (1u << b);
      int cnt = 0;
      #pragma unroll
      for (int i = 0; i < 4; i++) cnt += __popcll(__ballot(kk[i] >= cand));
      if (cnt >= 32) tau = cand;
    }
    unsigned long long bG[4], bE[4];
    int cntG = 0, sbG = 0, sbE = 0;
    #pragma unroll
    for (int i = 0; i < 4; i++) {
      bG[i] = __ballot(kk[i] > tau);
      bE[i] = __ballot(kk[i] == tau);
      cntG += __popcll(bG[i]);
      sbG  += lpc(bG[i]);
      sbE  += lpc(bE[i]);
    }
    const int need = 32 - cntG;
    int runG = 0, runE = 0;
    #pragma unroll
    for (int i = 0; i < 4; i++) {
      if (kk[i] > tau)       { tkbuf[w][sbG + runG] = mb + i; runG++; }
      else if (kk[i] == tau) {
        int r = sbE + runE;
        if (r < need) tkbuf[w][cntG + r] = mb + i;
        runE++;
      }
    }
  }
  __syncthreads();

  // ---- phase 2: wave w -> (head = w>>1, half = w&1), top-32 of 512 ----
  {
    const int h = w >> 1, half = w & 1;
    const float c00 = core[h * 4 + 0], c01 = core[h * 4 + 1];
    const float c10 = core[h * 4 + 2], c11 = core[h * 4 + 3];
    const int i_glob = half * 16 + (lane >> 2);
    const int ri = tkbuf[h * 2 + 0][i_glob];
    const float fr0 = s_pl[ri], fr1 = s_pl[256 + ri];
    const float a0 = fr0 * c00 + fr1 * c10;
    const float a1 = fr0 * c01 + fr1 * c11;
    const int j0 = (lane & 3) * 8;
    float sv[8];
    unsigned kk[8];
    #pragma unroll
    for (int t2 = 0; t2 < 8; t2++) {
      int cj = tkbuf[h * 2 + 1][j0 + t2];
      sv[t2] = a0 * s_pl[512 + cj] + a1 * s_pl[768 + cj];
      kk[t2] = f2ord(sv[t2]);
    }
    unsigned tau = 0u;
    #pragma unroll
    for (int b = 31; b >= 0; --b) {
      unsigned cand = tau | (1u << b);
      int cnt = 0;
      #pragma unroll
      for (int i = 0; i < 8; i++) cnt += __popcll(__ballot(kk[i] >= cand));
      if (cnt >= 32) tau = cand;
    }
    unsigned long long bG[8], bE[8];
    int cntG = 0, sbG = 0, sbE = 0;
    #pragma unroll
    for (int i = 0; i < 8; i++) {
      bG[i] = __ballot(kk[i] > tau);
      bE[i] = __ballot(kk[i] == tau);
      cntG += __popcll(bG[i]);
      sbG  += lpc(bG[i]);
      sbE  += lpc(bE[i]);
    }
    const int need = 32 - cntG;
    int runG = 0, runE = 0;
    #pragma unroll
    for (int i = 0; i < 8; i++) {
      int c = i_glob * 32 + j0 + i;
      if (kk[i] > tau) {
        mvals[w][sbG + runG] = sv[i]; mcand[w][sbG + runG] = c; runG++;
      } else if (kk[i] == tau) {
        int r = sbE + runE;
        if (r < need) { mvals[w][cntG + r] = sv[i]; mcand[w][cntG + r] = c; }
        runE++;
      }
    }
  }
  __syncthreads();

  // ---- merge two half-lists per head by rank-count ----
  if (w < 2) {
    const int h = w;
    const int half2 = lane >> 5, k = lane & 31;
    const float v = mvals[h * 2 + half2][k];
    const int   c = mcand[h * 2 + half2][k];
    int cnt = 0;
    #pragma unroll 8
    for (int j = 0; j < 64; j++) {
      float u = mvals[h * 2 + (j >> 5)][j & 31];
      int  uc = mcand[h * 2 + (j >> 5)][j & 31];
      cnt += (u > v || (u == v && uc < c)) ? 1 : 0;
    }
    if (cnt < 32) {
      int ii = c >> 5, jj = c & 31;
      s_idx[h * 32 + cnt] = tkbuf[h * 2][ii] * 256 + tkbuf[h * 2 + 1][jj];
      s_w[h * 32 + cnt]   = 1.0f / (1.0f + expf(-v));
    }
  }
  __syncthreads();

  // ---- weighted gather-sum: double-buffered batches of 8 loads ----
  const int h2 = tid >> 7;
  const int d4 = tid & 127;
  const int base = h2 * 32;
  const float* mb = memories + d4 * 4;
  float ax = 0.f, ay = 0.f, az = 0.f, aw = 0.f;
  float4 va[8], vb[8];
  float  wa[8], wb[8];
  #pragma unroll
  for (int i = 0; i < 8; i++) {
    int mi = s_idx[base + i]; wa[i] = s_w[base + i];
    va[i] = *(const float4*)(mb + (size_t)mi * 512);
  }
  #pragma unroll
  for (int i = 0; i < 8; i++) {
    int mi = s_idx[base + 8 + i]; wb[i] = s_w[base + 8 + i];
    vb[i] = *(const float4*)(mb + (size_t)mi * 512);
  }
  #pragma unroll
  for (int i = 0; i < 8; i++) {
    ax = fmaf(wa[i], va[i].x, ax); ay = fmaf(wa[i], va[i].y, ay);
    az = fmaf(wa[i], va[i].z, az); aw = fmaf(wa[i], va[i].w, aw);
  }
  #pragma unroll
  for (int i = 0; i < 8; i++) {
    int mi = s_idx[base + 16 + i]; wa[i] = s_w[base + 16 + i];
    va[i] = *(const float4*)(mb + (size_t)mi * 512);
  }
  #pragma unroll
  for (int i = 0; i < 8; i++) {
    ax = fmaf(wb[i], vb[i].x, ax); ay = fmaf(wb[i], vb[i].y, ay);
    az = fmaf(wb[i], vb[i].z, az); aw = fmaf(wb[i], vb[i].w, aw);
  }
  #pragma unroll
  for (int i = 0; i < 8; i++) {
    int mi = s_idx[base + 24 + i]; wb[i] = s_w[base + 24 + i];
    vb[i] = *(const float4*)(mb + (size_t)mi * 512);
  }
  #pragma unroll
  for (int i = 0; i < 8; i++) {
    ax = fmaf(wa[i], va[i].x, ax); ay = fmaf(wa[i], va[i].y, ay);
    az = fmaf(wa[i], va[i].z, az); aw = fmaf(wa[i], va[i].w, aw);
  }
  #pragma unroll
  for (int i = 0; i < 8; i++) {
    ax = fmaf(wb[i], vb[i].x, ax); ay = fmaf(wb[i], vb[i].y, ay);
    az = fmaf(wb[i], vb[i].z, az); aw = fmaf(wb[i], vb[i].w, aw);
  }
  float4 o4; o4.x = ax; o4.y = ay; o4.z = az; o4.w = aw;
  ((float4*)out)[(size_t)row * 256 + tid] = o4;
}

// ============================== launcher ====================================
extern "C" void kernel_launch(void* const* d_in, const int* in_sizes, int n_in,
                              void* d_out, int out_size, void* d_ws, size_t ws_size,
                              hipStream_t stream) {
  const float* tokens = (const float*)d_in[0];
  const float* rms_w  = (const float*)d_in[1];
  const float* conv_w = (const float*)d_in[2];
  const float* conv_b = (const float*)d_in[3];
  const float* wq     = (const float*)d_in[4];
  const float* qln_w  = (const float*)d_in[5];
  const float* keys   = (const float*)d_in[6];
  const float* core   = (const float*)d_in[7];
  const float* mems   = (const float*)d_in[8];
  float* out = (float*)d_out;
  float* ws  = (float*)d_ws;

  // workspace layout (floats); sc aliases x2 (dead after gemm1).
  float* misc   = ws;                          // 8
  float* x2     = ws + 4096;                   // 2048*1024
  float* qpart  = x2 + 2097152;                // 8 * 2048*128
  float* sc     = x2;

  conv_kernel  <<<ROWS / 8, 256, 0, stream>>>(tokens, rms_w, conv_w, conv_b,
                                              core, misc, out + 2097152, x2);
  gemm_kernel  <<<dim3(32, 8), 256, 0, stream>>>(x2, 1024, wq, 1024,
                                                 qpart, 128, 128, 0, ROWS * 128);
  gemm2ln_kernel<<<dim3(32, 8), 256, 0, stream>>>(qpart, qln_w, keys, sc);
  tail_kernel  <<<ROWS, 256, 0, stream>>>(sc, misc, core, mems, out);
}